// Round 1
// baseline (23558.049 us; speedup 1.0000x reference)
//
#include <hip/hip_runtime.h>

// PointerNetwork: B=2048, L=64, E=H=128, STEPS=126, out=(127,B,64) fp32.
// Design: one block per batch element, persistent over all 126 steps (batches
// are independent -> no grid sync). tanh-addition identity:
//   tanh(q+e) = (Tq+Te)/(1+Tq*Te), Te=tanh(e) precomputed once into registers.
// Raw e_g kept in LDS (padded) for the attention-weighted sum g_l.
// x@W_ih.T precomputed for all 64 candidate rows per batch (XW in workspace).

#define B_ 2048
#define L_ 64
#define H_ 128
#define STEPS_ 126
#define NEGV -1000000000.0f

__device__ __forceinline__ float fast_rcp(float x) { return __builtin_amdgcn_rcpf(x); }
__device__ __forceinline__ float sigm(float x) { return 1.0f / (1.0f + __expf(-x)); }

// ---------------- K1: XW = A[M,128] @ W[512,128]^T + (b1+b2) ----------------
__global__ __launch_bounds__(256) void xw_gemm(const float* __restrict__ A,
                                               const float* __restrict__ W,
                                               const float* __restrict__ b1,
                                               const float* __restrict__ b2,
                                               float* __restrict__ C) {
  __shared__ float As[64][36];
  __shared__ float Ws[64][36];
  const int t = threadIdx.x;
  const int tx = t & 15, ty = t >> 4;
  const long row0 = (long)blockIdx.x * 64;
  const int col0 = blockIdx.y * 64;
  float acc[4][4] = {};
  for (int k0 = 0; k0 < 128; k0 += 32) {
#pragma unroll
    for (int i = 0; i < 2; ++i) {
      int f4 = t * 2 + i;               // 0..511
      int r = f4 >> 3, c = (f4 & 7) * 4;
      *(float4*)&As[r][c] = *(const float4*)&A[(row0 + r) * 128 + k0 + c];
      *(float4*)&Ws[r][c] = *(const float4*)&W[(long)(col0 + r) * 128 + k0 + c];
    }
    __syncthreads();
#pragma unroll
    for (int kk = 0; kk < 32; kk += 4) {
      float4 a[4], w[4];
#pragma unroll
      for (int i = 0; i < 4; ++i) a[i] = *(float4*)&As[ty * 4 + i][kk];
#pragma unroll
      for (int j = 0; j < 4; ++j) w[j] = *(float4*)&Ws[tx * 4 + j][kk];
#pragma unroll
      for (int i = 0; i < 4; ++i)
#pragma unroll
        for (int j = 0; j < 4; ++j)
          acc[i][j] += a[i].x * w[j].x + a[i].y * w[j].y + a[i].z * w[j].z + a[i].w * w[j].w;
    }
    __syncthreads();
  }
#pragma unroll
  for (int i = 0; i < 4; ++i) {
    long r = row0 + ty * 4 + i;
#pragma unroll
    for (int j = 0; j < 4; ++j) {
      int cc = col0 + tx * 4 + j;
      C[r * 512 + cc] = acc[i][j] + b1[cc] + b2[cc];
    }
  }
}

// ---------------- main persistent kernel: one block per batch ----------------
__global__ __launch_bounds__(256, 2) void ptrnet_main(
    const float* __restrict__ dec, const float* __restrict__ emb,
    const float* __restrict__ ctx, const float* __restrict__ h0,
    const float* __restrict__ c0, const float* __restrict__ W_ih,
    const float* __restrict__ W_hh, const float* __restrict__ b_ih,
    const float* __restrict__ b_hh, const float* __restrict__ gWq,
    const float* __restrict__ gbq, const float* __restrict__ gWref,
    const float* __restrict__ gbref, const float* __restrict__ gv,
    const float* __restrict__ pWq, const float* __restrict__ pbq,
    const float* __restrict__ pWref, const float* __restrict__ pbref,
    const float* __restrict__ pv, const float* __restrict__ XW,
    const float* __restrict__ XW0, float* __restrict__ out, int use_precomp) {
  const int b = blockIdx.x;
  const int t = threadIdx.x;
  const int l = t & 63;       // this thread's column (position)
  const int hb = t >> 6;      // h-block: owns h = hb*32 .. hb*32+31

  __shared__ float egT[64][129];   // raw e_g transposed [l][h], pad->conflict-free
  __shared__ __align__(16) float hS[128];
  __shared__ float cS[128];
  __shared__ __align__(16) float glS[128];
  __shared__ float gatesS[512];
  __shared__ float aG[128], gvaG[128], aP[128], pvaG[128];
  __shared__ float gvS[128], pvS[128];
  __shared__ float wS[64];
  __shared__ float part[4][64];
  __shared__ float red2[2][128];
  __shared__ int maskS[64];
  __shared__ int curS;

  // ---- setup ----
  if (t < 128) {
    hS[t] = h0[(long)b * 128 + t];
    cS[t] = c0[(long)b * 128 + t];
    gvS[t] = gv[t];
    pvS[t] = pv[t];
  }
  if (t < 64) {
    maskS[t] = 0;
    out[(long)b * 64 + t] = (t == 0) ? 1.0f : 0.0f;  // prob0 row
  }
  if (t == 0) curS = 0;

  // e_g/e_p for (h = hb*32+k, l): accumulate into teg/tep, then tanh
  float teg[32], tep[32];
  {
    const float* crow = ctx + ((long)l * B_ + b) * 128;
#pragma unroll
    for (int k = 0; k < 32; ++k) {
      teg[k] = gbref[hb * 32 + k];
      tep[k] = pbref[hb * 32 + k];
    }
    for (int c4 = 0; c4 < 32; ++c4) {
      float4 cv = *(const float4*)&crow[c4 * 4];
#pragma unroll
      for (int k = 0; k < 32; ++k) {
        int h = hb * 32 + k;
        float4 wg = *(const float4*)&gWref[h * 128 + c4 * 4];
        float4 wp = *(const float4*)&pWref[h * 128 + c4 * 4];
        teg[k] += cv.x * wg.x + cv.y * wg.y + cv.z * wg.z + cv.w * wg.w;
        tep[k] += cv.x * wp.x + cv.y * wp.y + cv.z * wp.z + cv.w * wp.w;
      }
    }
#pragma unroll
    for (int k = 0; k < 32; ++k) {
      egT[l][hb * 32 + k] = teg[k];   // raw e_g for g_l
      teg[k] = tanhf(teg[k]);
      tep[k] = tanhf(tep[k]);
    }
  }
  __syncthreads();

  const float4* Whh4 = (const float4*)W_hh;
  const float4* hS4 = (const float4*)hS;
  const float4* glS4 = (const float4*)glS;

  for (int step = 0; step < STEPS_; ++step) {
    const int cur = curS;
    if (t == 0) {  // mask update with PREVIOUS chosen index
      maskS[cur] = 1;
      if (cur != 0) maskS[0] = 0;
    }

    // ---- gates: j = t and t+256 ----
    float acc0, acc1;
    if (use_precomp) {
      const float* xw = (step == 0) ? (XW0 + (long)b * 512)
                                    : (XW + ((long)cur * B_ + b) * 512);
      acc0 = xw[t];
      acc1 = xw[t + 256];
    } else {
      const float* xrow = (step == 0) ? (dec + (long)b * 128)
                                      : (emb + ((long)cur * B_ + b) * 128);
      acc0 = b_ih[t] + b_hh[t];
      acc1 = b_ih[t + 256] + b_hh[t + 256];
#pragma unroll
      for (int c4 = 0; c4 < 32; ++c4) {
        float4 xv = *(const float4*)&xrow[c4 * 4];
        float4 w0 = *(const float4*)&W_ih[(long)t * 128 + c4 * 4];
        float4 w1 = *(const float4*)&W_ih[(long)(t + 256) * 128 + c4 * 4];
        acc0 += xv.x * w0.x + xv.y * w0.y + xv.z * w0.z + xv.w * w0.w;
        acc1 += xv.x * w1.x + xv.y * w1.y + xv.z * w1.z + xv.w * w1.w;
      }
    }
#pragma unroll
    for (int c4 = 0; c4 < 32; ++c4) {
      float4 hv = hS4[c4];
      float4 w0 = Whh4[t * 32 + c4];
      float4 w1 = Whh4[(t + 256) * 32 + c4];
      acc0 += hv.x * w0.x + hv.y * w0.y + hv.z * w0.z + hv.w * w0.w;
      acc1 += hv.x * w1.x + hv.y * w1.y + hv.z * w1.z + hv.w * w1.w;
    }
    gatesS[t] = acc0;
    gatesS[t + 256] = acc1;
    __syncthreads();

    // ---- LSTM cell ----
    if (t < 128) {
      float gi = gatesS[t], gf = gatesS[t + 128];
      float gg = gatesS[t + 256], go = gatesS[t + 384];
      float cn = sigm(gf) * cS[t] + sigm(gi) * tanhf(gg);
      cS[t] = cn;
      hS[t] = sigm(go) * tanhf(cn);
    }
    __syncthreads();

    // ---- qg = h @ gWq^T + gbq ; Tq ----
    if (t < 128) {
      float acc = gbq[t];
#pragma unroll
      for (int c4 = 0; c4 < 32; ++c4) {
        float4 hv = hS4[c4];
        float4 w = *(const float4*)&gWq[(long)t * 128 + c4 * 4];
        acc += hv.x * w.x + hv.y * w.y + hv.z * w.z + hv.w * w.w;
      }
      float a = tanhf(acc);
      aG[t] = a;
      gvaG[t] = gvS[t] * a;
    }
    __syncthreads();

    // ---- ug partial: sum_h gv*(Tq+Te)/(1+Tq*Te) ----
    {
      float sum = 0.f;
#pragma unroll
      for (int k = 0; k < 32; ++k) {
        int h = hb * 32 + k;
        float te = teg[k];
        float den = fmaf(aG[h], te, 1.0f);
        float n2 = fmaf(gvS[h], te, gvaG[h]);
        sum = fmaf(n2, fast_rcp(den), sum);
      }
      part[hb][l] = sum;
    }
    __syncthreads();

    // ---- softmax over ug (wave 0) -> attention weights wS ----
    if (t < 64) {
      float u = part[0][l] + part[1][l] + part[2][l] + part[3][l];
      if (maskS[l]) u = NEGV;
      float m = u;
#pragma unroll
      for (int d = 32; d; d >>= 1) m = fmaxf(m, __shfl_xor(m, d));
      float e = __expf(u - m);
      float s = e;
#pragma unroll
      for (int d = 32; d; d >>= 1) s += __shfl_xor(s, d);
      wS[l] = e / s;
    }
    __syncthreads();

    // ---- g_l[h] = sum_l e_g[h,l]*w[l] ----
    {
      int h = t & 127, lh = t >> 7;
      float sum = 0.f;
#pragma unroll
      for (int q = 0; q < 32; ++q) {
        int l2 = lh * 32 + q;
        sum = fmaf(egT[l2][h], wS[l2], sum);
      }
      red2[lh][h] = sum;
    }
    __syncthreads();
    if (t < 128) glS[t] = red2[0][t] + red2[1][t];
    __syncthreads();

    // ---- qp = g_l @ pWq^T + pbq ; Tq_p ----
    if (t < 128) {
      float acc = pbq[t];
#pragma unroll
      for (int c4 = 0; c4 < 32; ++c4) {
        float4 gl = glS4[c4];
        float4 w = *(const float4*)&pWq[(long)t * 128 + c4 * 4];
        acc += gl.x * w.x + gl.y * w.y + gl.z * w.z + gl.w * w.w;
      }
      float a = tanhf(acc);
      aP[t] = a;
      pvaG[t] = pvS[t] * a;
    }
    __syncthreads();

    // ---- up partial ----
    {
      float sum = 0.f;
#pragma unroll
      for (int k = 0; k < 32; ++k) {
        int h = hb * 32 + k;
        float te = tep[k];
        float den = fmaf(aP[h], te, 1.0f);
        float n2 = fmaf(pvS[h], te, pvaG[h]);
        sum = fmaf(n2, fast_rcp(den), sum);
      }
      part[hb][l] = sum;
    }
    __syncthreads();

    // ---- final softmax + output + argmax (wave 0) ----
    if (t < 64) {
      float u = part[0][l] + part[1][l] + part[2][l] + part[3][l];
      u = 10.0f * tanhf(u);
      if (maskS[l]) u = NEGV;
      float m = u;
#pragma unroll
      for (int d = 32; d; d >>= 1) m = fmaxf(m, __shfl_xor(m, d));
      float e = __expf(u - m);
      float s = e;
#pragma unroll
      for (int d = 32; d; d >>= 1) s += __shfl_xor(s, d);
      float p = e / s;
      out[((long)(step + 1) * B_ + b) * 64 + l] = p;
      // argmax with first-index tie-break (matches numpy)
      float bv = p;
      int bi = l;
#pragma unroll
      for (int d = 32; d; d >>= 1) {
        float ov = __shfl_xor(bv, d);
        int oi = __shfl_xor(bi, d);
        if (ov > bv || (ov == bv && oi < bi)) { bv = ov; bi = oi; }
      }
      if (t == 0) curS = bi;
    }
    __syncthreads();
  }
}

extern "C" void kernel_launch(void* const* d_in, const int* in_sizes, int n_in,
                              void* d_out, int out_size, void* d_ws, size_t ws_size,
                              hipStream_t stream) {
  const float* dec = (const float*)d_in[0];
  const float* emb = (const float*)d_in[1];
  const float* ctx = (const float*)d_in[2];
  const float* h0 = (const float*)d_in[3];
  const float* c0 = (const float*)d_in[4];
  const float* Wih = (const float*)d_in[5];
  const float* Whh = (const float*)d_in[6];
  const float* bih = (const float*)d_in[7];
  const float* bhh = (const float*)d_in[8];
  const float* gWq = (const float*)d_in[9];
  const float* gbq = (const float*)d_in[10];
  const float* gWref = (const float*)d_in[11];
  const float* gbref = (const float*)d_in[12];
  const float* gv = (const float*)d_in[13];
  const float* pWq = (const float*)d_in[14];
  const float* pbq = (const float*)d_in[15];
  const float* pWref = (const float*)d_in[16];
  const float* pbref = (const float*)d_in[17];
  const float* pv = (const float*)d_in[18];
  float* out = (float*)d_out;

  const size_t xw_elems = (size_t)L_ * B_ * 512;
  const size_t need = (xw_elems + (size_t)B_ * 512) * sizeof(float);
  const int use_precomp = (ws_size >= need) ? 1 : 0;
  float* XW = (float*)d_ws;
  float* XW0 = XW + xw_elems;

  if (use_precomp) {
    dim3 g1((L_ * B_) / 64, 512 / 64);
    xw_gemm<<<g1, 256, 0, stream>>>(emb, Wih, bih, bhh, XW);
    dim3 g2(B_ / 64, 512 / 64);
    xw_gemm<<<g2, 256, 0, stream>>>(dec, Wih, bih, bhh, XW0);
  }
  ptrnet_main<<<dim3(B_), dim3(256), 0, stream>>>(
      dec, emb, ctx, h0, c0, Wih, Whh, bih, bhh, gWq, gbq, gWref, gbref, gv,
      pWq, pbq, pWref, pbref, pv, XW, XW0, out, use_precomp);
}

// Round 4
// 15238.304 us; speedup vs baseline: 1.5460x; 1.5460x over previous
//
#include <hip/hip_runtime.h>

// PointerNetwork: B=2048, L=64, E=H=128, STEPS=126, out=(127,B,64) fp32.
// One block (512 thr, 8 waves) per batch element, persistent over 126 steps.
// Weights are LOOP-RESIDENT ON-CHIP: W_hh row t in 128 VGPRs of thread t,
// gWq/pWq half-rows in 64 VGPRs (threads 0..255 / 256..511).
// tanh(e_g), tanh(e_p) precomputed once into LDS [h][l] (lane-consecutive l,
// conflict-free); raw e_g in LDS [l][h] for the attention-weighted sum.
// tanh-addition identity: tanh(q+e) = (Tq+Te)/(1+Tq*Te) with v_rcp.
// x@W_ih.T precomputed into workspace (XW) by a small GEMM.

#define B_ 2048
#define L_ 64
#define H_ 128
#define STEPS_ 126
#define NEGV -1000000000.0f

__device__ __forceinline__ float fast_rcp(float x) { return __builtin_amdgcn_rcpf(x); }
__device__ __forceinline__ float sigm(float x) { return 1.0f / (1.0f + __expf(-x)); }
__device__ __forceinline__ float dot4(float4 a, float4 b) {
  return a.x * b.x + a.y * b.y + a.z * b.z + a.w * b.w;
}

// ---------------- K1: XW = A[M,128] @ W[512,128]^T + (b1+b2) ----------------
__global__ __launch_bounds__(256) void xw_gemm(const float* __restrict__ A,
                                               const float* __restrict__ W,
                                               const float* __restrict__ b1,
                                               const float* __restrict__ b2,
                                               float* __restrict__ C) {
  __shared__ float As[64][36];
  __shared__ float Ws[64][36];
  const int t = threadIdx.x;
  const int tx = t & 15, ty = t >> 4;
  const long row0 = (long)blockIdx.x * 64;
  const int col0 = blockIdx.y * 64;
  float acc[4][4] = {};
  for (int k0 = 0; k0 < 128; k0 += 32) {
#pragma unroll
    for (int i = 0; i < 2; ++i) {
      int f4 = t * 2 + i;
      int r = f4 >> 3, c = (f4 & 7) * 4;
      *(float4*)&As[r][c] = *(const float4*)&A[(row0 + r) * 128 + k0 + c];
      *(float4*)&Ws[r][c] = *(const float4*)&W[(long)(col0 + r) * 128 + k0 + c];
    }
    __syncthreads();
#pragma unroll
    for (int kk = 0; kk < 32; kk += 4) {
      float4 a[4], w[4];
#pragma unroll
      for (int i = 0; i < 4; ++i) a[i] = *(float4*)&As[ty * 4 + i][kk];
#pragma unroll
      for (int j = 0; j < 4; ++j) w[j] = *(float4*)&Ws[tx * 4 + j][kk];
#pragma unroll
      for (int i = 0; i < 4; ++i)
#pragma unroll
        for (int j = 0; j < 4; ++j)
          acc[i][j] += dot4(a[i], w[j]);
    }
    __syncthreads();
  }
#pragma unroll
  for (int i = 0; i < 4; ++i) {
    long r = row0 + ty * 4 + i;
#pragma unroll
    for (int j = 0; j < 4; ++j) {
      int cc = col0 + tx * 4 + j;
      C[r * 512 + cc] = acc[i][j] + b1[cc] + b2[cc];
    }
  }
}

// ---------------- main persistent kernel: one block per batch ----------------
__global__ __launch_bounds__(512, 2) void ptrnet_main(
    const float* __restrict__ dec, const float* __restrict__ emb,
    const float* __restrict__ ctx, const float* __restrict__ h0,
    const float* __restrict__ c0, const float* __restrict__ W_ih,
    const float* __restrict__ W_hh, const float* __restrict__ b_ih,
    const float* __restrict__ b_hh, const float* __restrict__ gWq,
    const float* __restrict__ gbq, const float* __restrict__ gWref,
    const float* __restrict__ gbref, const float* __restrict__ gv,
    const float* __restrict__ pWq, const float* __restrict__ pbq,
    const float* __restrict__ pWref, const float* __restrict__ pbref,
    const float* __restrict__ pv, const float* __restrict__ XW,
    const float* __restrict__ XW0, float* __restrict__ out, int use_precomp) {
  const int b = blockIdx.x;
  const int t = threadIdx.x;
  const int l = t & 63;   // attn column owned by this thread
  const int hb = t >> 6;  // 0..7: owns h in [hb*16, hb*16+16)

  __shared__ float tegS[128][64];  // tanh(e_g), [h][l] layout (conflict-free)
  __shared__ float tepS[128][64];  // tanh(e_p)
  __shared__ float egT[64][128];   // raw e_g, [l][h]
  __shared__ __align__(16) float hS[128];
  __shared__ float cS[128];
  __shared__ __align__(16) float glS[128];
  __shared__ __align__(16) float xS[128];
  __shared__ float gatesS[512];
  __shared__ __align__(16) float aG[128];
  __shared__ __align__(16) float gvaG[128];
  __shared__ __align__(16) float aP[128];
  __shared__ __align__(16) float pvaP[128];
  __shared__ __align__(16) float gvS[128];
  __shared__ __align__(16) float pvS[128];
  __shared__ float gbqS[128], pbqS[128];
  __shared__ float bS[512];
  __shared__ float wS[64];
  __shared__ float part[8][64];
  __shared__ float red4[4][128];
  __shared__ int maskS[64];
  __shared__ int curS;

  // ---- setup ----
  if (t < 128) {
    hS[t] = h0[(long)b * 128 + t];
    cS[t] = c0[(long)b * 128 + t];
    gvS[t] = gv[t];
    pvS[t] = pv[t];
    gbqS[t] = gbq[t];
    pbqS[t] = pbq[t];
  }
  bS[t] = b_ih[t] + b_hh[t];
  if (t < 64) {
    maskS[t] = 0;
    out[(long)b * 64 + t] = (t == 0) ? 1.0f : 0.0f;  // prob0 row
  }
  if (t == 0) curS = 0;

  // e_g / e_p: thread (l, hb) computes 16 h-rows
  {
    const float4* crow4 = (const float4*)(ctx + ((long)l * B_ + b) * 128);
    for (int k = 0; k < 16; ++k) {
      int h = hb * 16 + k;
      float eg = gbref[h], ep = pbref[h];
      const float4* wg4 = (const float4*)(gWref + (long)h * 128);
      const float4* wp4 = (const float4*)(pWref + (long)h * 128);
#pragma unroll
      for (int c = 0; c < 32; ++c) {
        float4 cv = crow4[c];
        eg += dot4(cv, wg4[c]);
        ep += dot4(cv, wp4[c]);
      }
      egT[l][h] = eg;
      tegS[h][l] = tanhf(eg);
      tepS[h][l] = tanhf(ep);
    }
  }

  // loop-resident weights in registers
  float4 whh[32];
  const float4* Whh4 = (const float4*)W_hh;
#pragma unroll
  for (int c = 0; c < 32; ++c) whh[c] = Whh4[(long)t * 32 + c];
  float4 qw[16];
  {
    const float4* Q4 = (t < 256) ? (const float4*)gWq : (const float4*)pWq;
    int j = (t & 255) >> 1, half = t & 1;
#pragma unroll
    for (int c = 0; c < 16; ++c) qw[c] = Q4[(long)j * 32 + half * 16 + c];
  }
  __syncthreads();

  const float4* hS4 = (const float4*)hS;
  const float4* glS4 = (const float4*)glS;
  const float4* xS4 = (const float4*)xS;
  float4* xS4w = (float4*)xS;

  for (int step = 0; step < STEPS_; ++step) {
    const int cur = curS;
    if (t == 0) {  // mask update with PREVIOUS chosen index
      maskS[cur] = 1;
      if (cur != 0) maskS[0] = 0;
    }

    // ---- phase 1 (fallback only): stage x row ----
    if (!use_precomp) {
      if (t < 32)
        xS4w[t] = (step == 0) ? ((const float4*)(dec + (long)b * 128))[t]
                              : ((const float4*)(emb + ((long)cur * B_ + b) * 128))[t];
      __syncthreads();
    }

    // ---- gates: thread t owns output row t ----
    float xv;
    if (use_precomp) {
      const float* xw = (step == 0) ? (XW0 + (long)b * 512)
                                    : (XW + ((long)cur * B_ + b) * 512);
      xv = xw[t];  // issued early, consumed after the W_hh dot
    } else {
      xv = bS[t];
      const float4* wih4 = (const float4*)(W_ih + (long)t * 128);
#pragma unroll
      for (int c = 0; c < 32; ++c) xv += dot4(wih4[c], xS4[c]);
    }
    {
      float acc = 0.f;
#pragma unroll
      for (int c = 0; c < 32; ++c) acc += dot4(whh[c], hS4[c]);
      gatesS[t] = acc + xv;
    }
    __syncthreads();

    // ---- LSTM cell ----
    if (t < 128) {
      float gi = gatesS[t], gf = gatesS[t + 128];
      float gg = gatesS[t + 256], go = gatesS[t + 384];
      float cn = sigm(gf) * cS[t] + sigm(gi) * tanhf(gg);
      cS[t] = cn;
      hS[t] = sigm(go) * tanhf(cn);
    }
    __syncthreads();

    // ---- qg = h @ gWq^T + gbq (threads 0..255, half-rows) ----
    if (t < 256) {
      int j = t >> 1, half = t & 1;
      float p = 0.f;
#pragma unroll
      for (int c = 0; c < 16; ++c) p += dot4(qw[c], hS4[half * 16 + c]);
      p += __shfl_xor(p, 1);
      if (half == 0) {
        float a = tanhf(p + gbqS[j]);
        aG[j] = a;
        gvaG[j] = gvS[j] * a;
      }
    }
    __syncthreads();

    // ---- ug partials: sum_h gv*(Tq+Te)/(1+Tq*Te) ----
    {
      const float4* a4 = (const float4*)aG;
      const float4* g4 = (const float4*)gvS;
      const float4* ga4 = (const float4*)gvaG;
      float4 av[4], gv4[4], gav[4];
#pragma unroll
      for (int i = 0; i < 4; ++i) {
        av[i] = a4[hb * 4 + i];
        gv4[i] = g4[hb * 4 + i];
        gav[i] = ga4[hb * 4 + i];
      }
      const float* af = (const float*)av;
      const float* gf = (const float*)gv4;
      const float* gaf = (const float*)gav;
      float sum = 0.f;
#pragma unroll
      for (int k = 0; k < 16; ++k) {
        float te = tegS[hb * 16 + k][l];
        float den = fmaf(af[k], te, 1.0f);
        float n2 = fmaf(gf[k], te, gaf[k]);
        sum = fmaf(n2, fast_rcp(den), sum);
      }
      part[hb][l] = sum;
    }
    __syncthreads();

    // ---- softmax over ug (wave 0) -> attention weights wS ----
    if (t < 64) {
      float u = part[0][l] + part[1][l] + part[2][l] + part[3][l] +
                part[4][l] + part[5][l] + part[6][l] + part[7][l];
      if (maskS[l]) u = NEGV;
      float m = u;
#pragma unroll
      for (int d = 32; d; d >>= 1) m = fmaxf(m, __shfl_xor(m, d));
      float e = __expf(u - m);
      float s = e;
#pragma unroll
      for (int d = 32; d; d >>= 1) s += __shfl_xor(s, d);
      wS[l] = e / s;
    }
    __syncthreads();

    // ---- g_l[h] = sum_l e_g[h,l]*w[l] ----
    {
      int h = t & 127, lh = t >> 7;
      float sum = 0.f;
#pragma unroll
      for (int q = 0; q < 16; ++q) {
        int l2 = lh * 16 + q;
        sum = fmaf(egT[l2][h], wS[l2], sum);
      }
      red4[lh][h] = sum;
    }
    __syncthreads();
    if (t < 128) glS[t] = red4[0][t] + red4[1][t] + red4[2][t] + red4[3][t];
    __syncthreads();

    // ---- qp = g_l @ pWq^T + pbq (threads 256..511, half-rows) ----
    if (t >= 256) {
      int j = (t - 256) >> 1, half = t & 1;
      float p = 0.f;
#pragma unroll
      for (int c = 0; c < 16; ++c) p += dot4(qw[c], glS4[half * 16 + c]);
      p += __shfl_xor(p, 1);
      if (half == 0) {
        float a = tanhf(p + pbqS[j]);
        aP[j] = a;
        pvaP[j] = pvS[j] * a;
      }
    }
    __syncthreads();

    // ---- up partials ----
    {
      const float4* a4 = (const float4*)aP;
      const float4* p4 = (const float4*)pvS;
      const float4* pa4 = (const float4*)pvaP;
      float4 av[4], pv4[4], pav[4];
#pragma unroll
      for (int i = 0; i < 4; ++i) {
        av[i] = a4[hb * 4 + i];
        pv4[i] = p4[hb * 4 + i];
        pav[i] = pa4[hb * 4 + i];
      }
      const float* af = (const float*)av;
      const float* pf = (const float*)pv4;
      const float* paf = (const float*)pav;
      float sum = 0.f;
#pragma unroll
      for (int k = 0; k < 16; ++k) {
        float te = tepS[hb * 16 + k][l];
        float den = fmaf(af[k], te, 1.0f);
        float n2 = fmaf(pf[k], te, paf[k]);
        sum = fmaf(n2, fast_rcp(den), sum);
      }
      part[hb][l] = sum;
    }
    __syncthreads();

    // ---- final softmax + output + argmax (wave 0) ----
    if (t < 64) {
      float u = part[0][l] + part[1][l] + part[2][l] + part[3][l] +
                part[4][l] + part[5][l] + part[6][l] + part[7][l];
      u = 10.0f * tanhf(u);
      if (maskS[l]) u = NEGV;
      float m = u;
#pragma unroll
      for (int d = 32; d; d >>= 1) m = fmaxf(m, __shfl_xor(m, d));
      float e = __expf(u - m);
      float s = e;
#pragma unroll
      for (int d = 32; d; d >>= 1) s += __shfl_xor(s, d);
      float p = e / s;
      out[((long)(step + 1) * B_ + b) * 64 + l] = p;
      // argmax with first-index tie-break (matches numpy)
      float bv = p;
      int bi = l;
#pragma unroll
      for (int d = 32; d; d >>= 1) {
        float ov = __shfl_xor(bv, d);
        int oi = __shfl_xor(bi, d);
        if (ov > bv || (ov == bv && oi < bi)) { bv = ov; bi = oi; }
      }
      if (t == 0) curS = bi;
    }
    __syncthreads();
  }
}

extern "C" void kernel_launch(void* const* d_in, const int* in_sizes, int n_in,
                              void* d_out, int out_size, void* d_ws, size_t ws_size,
                              hipStream_t stream) {
  const float* dec = (const float*)d_in[0];
  const float* emb = (const float*)d_in[1];
  const float* ctx = (const float*)d_in[2];
  const float* h0 = (const float*)d_in[3];
  const float* c0 = (const float*)d_in[4];
  const float* Wih = (const float*)d_in[5];
  const float* Whh = (const float*)d_in[6];
  const float* bih = (const float*)d_in[7];
  const float* bhh = (const float*)d_in[8];
  const float* gWq = (const float*)d_in[9];
  const float* gbq = (const float*)d_in[10];
  const float* gWref = (const float*)d_in[11];
  const float* gbref = (const float*)d_in[12];
  const float* gv = (const float*)d_in[13];
  const float* pWq = (const float*)d_in[14];
  const float* pbq = (const float*)d_in[15];
  const float* pWref = (const float*)d_in[16];
  const float* pbref = (const float*)d_in[17];
  const float* pv = (const float*)d_in[18];
  float* out = (float*)d_out;

  const size_t xw_elems = (size_t)L_ * B_ * 512;
  const size_t need = (xw_elems + (size_t)B_ * 512) * sizeof(float);
  const int use_precomp = (ws_size >= need) ? 1 : 0;
  float* XW = (float*)d_ws;
  float* XW0 = XW + xw_elems;

  if (use_precomp) {
    dim3 g1((L_ * B_) / 64, 512 / 64);
    xw_gemm<<<g1, 256, 0, stream>>>(emb, Wih, bih, bhh, XW);
    dim3 g2(B_ / 64, 512 / 64);
    xw_gemm<<<g2, 256, 0, stream>>>(dec, Wih, bih, bhh, XW0);
  }
  ptrnet_main<<<dim3(B_), dim3(512), 0, stream>>>(
      dec, emb, ctx, h0, c0, Wih, Whh, bih, bhh, gWq, gbq, gWref, gbref, gv,
      pWq, pbq, pWref, pbref, pv, XW, XW0, out, use_precomp);
}

// Round 5
// 15177.574 us; speedup vs baseline: 1.5522x; 1.0040x over previous
//
#include <hip/hip_runtime.h>

// PointerNetwork: B=2048, L=64, E=H=128, STEPS=126, out=(127,B,64) fp32.
// One block (512 thr, 8 waves) per batch element, persistent over 126 steps.
// Weights are LOOP-RESIDENT ON-CHIP: W_hh row t in 128 VGPRs of thread t,
// gWq/pWq half-rows in 64 VGPRs (threads 0..255 / 256..511).
// __launch_bounds__(512, 1): 2nd arg is min BLOCKS/CU (CUDA semantics) --
// (512,2) capped VGPRs at 128 and spilled the weight arrays to scratch
// (measured: VGPR_Count=128, 15 us/step). (512,1) -> cap 512, ~230 used.
// tanh(e_g), tanh(e_p) in LDS [h][l] (lane-consecutive l, conflict-free);
// raw e_g in LDS [l][h] for the attention-weighted sum.
// tanh-addition identity: tanh(q+e) = (Tq+Te)/(1+Tq*Te) with v_rcp.
// x@W_ih.T precomputed into workspace (XW) by a small GEMM.

#define B_ 2048
#define L_ 64
#define H_ 128
#define STEPS_ 126
#define NEGV -1000000000.0f

__device__ __forceinline__ float fast_rcp(float x) { return __builtin_amdgcn_rcpf(x); }
__device__ __forceinline__ float sigm(float x) { return 1.0f / (1.0f + __expf(-x)); }
__device__ __forceinline__ float dot4(float4 a, float4 b) {
  return a.x * b.x + a.y * b.y + a.z * b.z + a.w * b.w;
}

// ---------------- K1: XW = A[M,128] @ W[512,128]^T + (b1+b2) ----------------
__global__ __launch_bounds__(256) void xw_gemm(const float* __restrict__ A,
                                               const float* __restrict__ W,
                                               const float* __restrict__ b1,
                                               const float* __restrict__ b2,
                                               float* __restrict__ C) {
  __shared__ float As[64][36];
  __shared__ float Ws[64][36];
  const int t = threadIdx.x;
  const int tx = t & 15, ty = t >> 4;
  const long row0 = (long)blockIdx.x * 64;
  const int col0 = blockIdx.y * 64;
  float acc[4][4] = {};
  for (int k0 = 0; k0 < 128; k0 += 32) {
#pragma unroll
    for (int i = 0; i < 2; ++i) {
      int f4 = t * 2 + i;
      int r = f4 >> 3, c = (f4 & 7) * 4;
      *(float4*)&As[r][c] = *(const float4*)&A[(row0 + r) * 128 + k0 + c];
      *(float4*)&Ws[r][c] = *(const float4*)&W[(long)(col0 + r) * 128 + k0 + c];
    }
    __syncthreads();
#pragma unroll
    for (int kk = 0; kk < 32; kk += 4) {
      float4 a[4], w[4];
#pragma unroll
      for (int i = 0; i < 4; ++i) a[i] = *(float4*)&As[ty * 4 + i][kk];
#pragma unroll
      for (int j = 0; j < 4; ++j) w[j] = *(float4*)&Ws[tx * 4 + j][kk];
#pragma unroll
      for (int i = 0; i < 4; ++i)
#pragma unroll
        for (int j = 0; j < 4; ++j)
          acc[i][j] += dot4(a[i], w[j]);
    }
    __syncthreads();
  }
#pragma unroll
  for (int i = 0; i < 4; ++i) {
    long r = row0 + ty * 4 + i;
#pragma unroll
    for (int j = 0; j < 4; ++j) {
      int cc = col0 + tx * 4 + j;
      C[r * 512 + cc] = acc[i][j] + b1[cc] + b2[cc];
    }
  }
}

// ---------------- main persistent kernel: one block per batch ----------------
__global__ __launch_bounds__(512, 1) void ptrnet_main(
    const float* __restrict__ dec, const float* __restrict__ emb,
    const float* __restrict__ ctx, const float* __restrict__ h0,
    const float* __restrict__ c0, const float* __restrict__ W_ih,
    const float* __restrict__ W_hh, const float* __restrict__ b_ih,
    const float* __restrict__ b_hh, const float* __restrict__ gWq,
    const float* __restrict__ gbq, const float* __restrict__ gWref,
    const float* __restrict__ gbref, const float* __restrict__ gv,
    const float* __restrict__ pWq, const float* __restrict__ pbq,
    const float* __restrict__ pWref, const float* __restrict__ pbref,
    const float* __restrict__ pv, const float* __restrict__ XW,
    const float* __restrict__ XW0, float* __restrict__ out, int use_precomp) {
  const int b = blockIdx.x;
  const int t = threadIdx.x;
  const int l = t & 63;   // attn column owned by this thread
  const int hb = t >> 6;  // 0..7: owns h in [hb*16, hb*16+16)

  __shared__ float tegS[128][64];  // tanh(e_g), [h][l] layout (conflict-free)
  __shared__ float tepS[128][64];  // tanh(e_p)
  __shared__ float egT[64][128];   // raw e_g, [l][h]
  __shared__ __align__(16) float hS[128];
  __shared__ float cS[128];
  __shared__ __align__(16) float glS[128];
  __shared__ __align__(16) float xS[128];
  __shared__ float gatesS[512];
  __shared__ __align__(16) float aG[128];
  __shared__ __align__(16) float gvaG[128];
  __shared__ __align__(16) float aP[128];
  __shared__ __align__(16) float pvaP[128];
  __shared__ __align__(16) float gvS[128];
  __shared__ __align__(16) float pvS[128];
  __shared__ float gbqS[128], pbqS[128];
  __shared__ float bS[512];
  __shared__ float wS[64];
  __shared__ float part[8][64];
  __shared__ float red4[4][128];
  __shared__ int maskS[64];
  __shared__ int curS;

  // ---- setup ----
  if (t < 128) {
    hS[t] = h0[(long)b * 128 + t];
    cS[t] = c0[(long)b * 128 + t];
    gvS[t] = gv[t];
    pvS[t] = pv[t];
    gbqS[t] = gbq[t];
    pbqS[t] = pbq[t];
  }
  bS[t] = b_ih[t] + b_hh[t];
  if (t < 64) {
    maskS[t] = 0;
    out[(long)b * 64 + t] = (t == 0) ? 1.0f : 0.0f;  // prob0 row
  }
  if (t == 0) curS = 0;

  // e_g / e_p: thread (l, hb) computes 16 h-rows
  {
    const float4* crow4 = (const float4*)(ctx + ((long)l * B_ + b) * 128);
    for (int k = 0; k < 16; ++k) {
      int h = hb * 16 + k;
      float eg = gbref[h], ep = pbref[h];
      const float4* wg4 = (const float4*)(gWref + (long)h * 128);
      const float4* wp4 = (const float4*)(pWref + (long)h * 128);
#pragma unroll
      for (int c = 0; c < 32; ++c) {
        float4 cv = crow4[c];
        eg += dot4(cv, wg4[c]);
        ep += dot4(cv, wp4[c]);
      }
      egT[l][h] = eg;
      tegS[h][l] = tanhf(eg);
      tepS[h][l] = tanhf(ep);
    }
  }

  // loop-resident weights in registers
  float4 whh[32];
  const float4* Whh4 = (const float4*)W_hh;
#pragma unroll
  for (int c = 0; c < 32; ++c) whh[c] = Whh4[(long)t * 32 + c];
  float4 qw[16];
  {
    const float4* Q4 = (t < 256) ? (const float4*)gWq : (const float4*)pWq;
    int j = (t & 255) >> 1, half = t & 1;
#pragma unroll
    for (int c = 0; c < 16; ++c) qw[c] = Q4[(long)j * 32 + half * 16 + c];
  }
  __syncthreads();

  const float4* hS4 = (const float4*)hS;
  const float4* glS4 = (const float4*)glS;
  const float4* xS4 = (const float4*)xS;
  float4* xS4w = (float4*)xS;

  for (int step = 0; step < STEPS_; ++step) {
    const int cur = curS;
    if (t == 0) {  // mask update with PREVIOUS chosen index
      maskS[cur] = 1;
      if (cur != 0) maskS[0] = 0;
    }

    // ---- phase 1 (fallback only): stage x row ----
    if (!use_precomp) {
      if (t < 32)
        xS4w[t] = (step == 0) ? ((const float4*)(dec + (long)b * 128))[t]
                              : ((const float4*)(emb + ((long)cur * B_ + b) * 128))[t];
      __syncthreads();
    }

    // ---- gates: thread t owns output row t ----
    float xv;
    if (use_precomp) {
      const float* xw = (step == 0) ? (XW0 + (long)b * 512)
                                    : (XW + ((long)cur * B_ + b) * 512);
      xv = xw[t];  // issued early, consumed after the W_hh dot
    } else {
      xv = bS[t];
      const float4* wih4 = (const float4*)(W_ih + (long)t * 128);
#pragma unroll
      for (int c = 0; c < 32; ++c) xv += dot4(wih4[c], xS4[c]);
    }
    {
      float acc = 0.f;
#pragma unroll
      for (int c = 0; c < 32; ++c) acc += dot4(whh[c], hS4[c]);
      gatesS[t] = acc + xv;
    }
    __syncthreads();

    // ---- LSTM cell ----
    if (t < 128) {
      float gi = gatesS[t], gf = gatesS[t + 128];
      float gg = gatesS[t + 256], go = gatesS[t + 384];
      float cn = sigm(gf) * cS[t] + sigm(gi) * tanhf(gg);
      cS[t] = cn;
      hS[t] = sigm(go) * tanhf(cn);
    }
    __syncthreads();

    // ---- qg = h @ gWq^T + gbq (threads 0..255, half-rows) ----
    if (t < 256) {
      int j = t >> 1, half = t & 1;
      float p = 0.f;
#pragma unroll
      for (int c = 0; c < 16; ++c) p += dot4(qw[c], hS4[half * 16 + c]);
      p += __shfl_xor(p, 1);
      if (half == 0) {
        float a = tanhf(p + gbqS[j]);
        aG[j] = a;
        gvaG[j] = gvS[j] * a;
      }
    }
    __syncthreads();

    // ---- ug partials: sum_h gv*(Tq+Te)/(1+Tq*Te) ----
    {
      const float4* a4 = (const float4*)aG;
      const float4* g4 = (const float4*)gvS;
      const float4* ga4 = (const float4*)gvaG;
      float4 av[4], gv4[4], gav[4];
#pragma unroll
      for (int i = 0; i < 4; ++i) {
        av[i] = a4[hb * 4 + i];
        gv4[i] = g4[hb * 4 + i];
        gav[i] = ga4[hb * 4 + i];
      }
      const float* af = (const float*)av;
      const float* gf = (const float*)gv4;
      const float* gaf = (const float*)gav;
      float sum = 0.f;
#pragma unroll
      for (int k = 0; k < 16; ++k) {
        float te = tegS[hb * 16 + k][l];
        float den = fmaf(af[k], te, 1.0f);
        float n2 = fmaf(gf[k], te, gaf[k]);
        sum = fmaf(n2, fast_rcp(den), sum);
      }
      part[hb][l] = sum;
    }
    __syncthreads();

    // ---- softmax over ug (wave 0) -> attention weights wS ----
    if (t < 64) {
      float u = part[0][l] + part[1][l] + part[2][l] + part[3][l] +
                part[4][l] + part[5][l] + part[6][l] + part[7][l];
      if (maskS[l]) u = NEGV;
      float m = u;
#pragma unroll
      for (int d = 32; d; d >>= 1) m = fmaxf(m, __shfl_xor(m, d));
      float e = __expf(u - m);
      float s = e;
#pragma unroll
      for (int d = 32; d; d >>= 1) s += __shfl_xor(s, d);
      wS[l] = e / s;
    }
    __syncthreads();

    // ---- g_l[h] = sum_l e_g[h,l]*w[l] ----
    {
      int h = t & 127, lh = t >> 7;
      float sum = 0.f;
#pragma unroll
      for (int q = 0; q < 16; ++q) {
        int l2 = lh * 16 + q;
        sum = fmaf(egT[l2][h], wS[l2], sum);
      }
      red4[lh][h] = sum;
    }
    __syncthreads();
    if (t < 128) glS[t] = red4[0][t] + red4[1][t] + red4[2][t] + red4[3][t];
    __syncthreads();

    // ---- qp = g_l @ pWq^T + pbq (threads 256..511, half-rows) ----
    if (t >= 256) {
      int j = (t - 256) >> 1, half = t & 1;
      float p = 0.f;
#pragma unroll
      for (int c = 0; c < 16; ++c) p += dot4(qw[c], glS4[half * 16 + c]);
      p += __shfl_xor(p, 1);
      if (half == 0) {
        float a = tanhf(p + pbqS[j]);
        aP[j] = a;
        pvaP[j] = pvS[j] * a;
      }
    }
    __syncthreads();

    // ---- up partials ----
    {
      const float4* a4 = (const float4*)aP;
      const float4* p4 = (const float4*)pvS;
      const float4* pa4 = (const float4*)pvaP;
      float4 av[4], pv4[4], pav[4];
#pragma unroll
      for (int i = 0; i < 4; ++i) {
        av[i] = a4[hb * 4 + i];
        pv4[i] = p4[hb * 4 + i];
        pav[i] = pa4[hb * 4 + i];
      }
      const float* af = (const float*)av;
      const float* pf = (const float*)pv4;
      const float* paf = (const float*)pav;
      float sum = 0.f;
#pragma unroll
      for (int k = 0; k < 16; ++k) {
        float te = tepS[hb * 16 + k][l];
        float den = fmaf(af[k], te, 1.0f);
        float n2 = fmaf(pf[k], te, paf[k]);
        sum = fmaf(n2, fast_rcp(den), sum);
      }
      part[hb][l] = sum;
    }
    __syncthreads();

    // ---- final softmax + output + argmax (wave 0) ----
    if (t < 64) {
      float u = part[0][l] + part[1][l] + part[2][l] + part[3][l] +
                part[4][l] + part[5][l] + part[6][l] + part[7][l];
      u = 10.0f * tanhf(u);
      if (maskS[l]) u = NEGV;
      float m = u;
#pragma unroll
      for (int d = 32; d; d >>= 1) m = fmaxf(m, __shfl_xor(m, d));
      float e = __expf(u - m);
      float s = e;
#pragma unroll
      for (int d = 32; d; d >>= 1) s += __shfl_xor(s, d);
      float p = e / s;
      out[((long)(step + 1) * B_ + b) * 64 + l] = p;
      // argmax with first-index tie-break (matches numpy)
      float bv = p;
      int bi = l;
#pragma unroll
      for (int d = 32; d; d >>= 1) {
        float ov = __shfl_xor(bv, d);
        int oi = __shfl_xor(bi, d);
        if (ov > bv || (ov == bv && oi < bi)) { bv = ov; bi = oi; }
      }
      if (t == 0) curS = bi;
    }
    __syncthreads();
  }
}

extern "C" void kernel_launch(void* const* d_in, const int* in_sizes, int n_in,
                              void* d_out, int out_size, void* d_ws, size_t ws_size,
                              hipStream_t stream) {
  const float* dec = (const float*)d_in[0];
  const float* emb = (const float*)d_in[1];
  const float* ctx = (const float*)d_in[2];
  const float* h0 = (const float*)d_in[3];
  const float* c0 = (const float*)d_in[4];
  const float* Wih = (const float*)d_in[5];
  const float* Whh = (const float*)d_in[6];
  const float* bih = (const float*)d_in[7];
  const float* bhh = (const float*)d_in[8];
  const float* gWq = (const float*)d_in[9];
  const float* gbq = (const float*)d_in[10];
  const float* gWref = (const float*)d_in[11];
  const float* gbref = (const float*)d_in[12];
  const float* gv = (const float*)d_in[13];
  const float* pWq = (const float*)d_in[14];
  const float* pbq = (const float*)d_in[15];
  const float* pWref = (const float*)d_in[16];
  const float* pbref = (const float*)d_in[17];
  const float* pv = (const float*)d_in[18];
  float* out = (float*)d_out;

  const size_t xw_elems = (size_t)L_ * B_ * 512;
  const size_t need = (xw_elems + (size_t)B_ * 512) * sizeof(float);
  const int use_precomp = (ws_size >= need) ? 1 : 0;
  float* XW = (float*)d_ws;
  float* XW0 = XW + xw_elems;

  if (use_precomp) {
    dim3 g1((L_ * B_) / 64, 512 / 64);
    xw_gemm<<<g1, 256, 0, stream>>>(emb, Wih, bih, bhh, XW);
    dim3 g2(B_ / 64, 512 / 64);
    xw_gemm<<<g2, 256, 0, stream>>>(dec, Wih, bih, bhh, XW0);
  }
  ptrnet_main<<<dim3(B_), dim3(512), 0, stream>>>(
      dec, emb, ctx, h0, c0, Wih, Whh, bih, bhh, gWq, gbq, gWref, gbref, gv,
      pWq, pbq, pWref, pbref, pv, XW, XW0, out, use_precomp);
}